// Round 3
// baseline (1876.914 us; speedup 1.0000x reference)
//
#include <hip/hip_runtime.h>
#include <hip/hip_bf16.h>

#define N_ 100000
#define E_ 1600000
#define D_ 128
#define H_ 4
#define C_ 32

using bf16 = __hip_bfloat16;

__device__ __forceinline__ float b2f(bf16 v) { return __bfloat162float(v); }
__device__ __forceinline__ float u2f(unsigned u) { return __uint_as_float(u); }
__device__ __forceinline__ unsigned short f2bu(float v) {
  bf16 t = __float2bfloat16(v);
  return *(unsigned short*)&t;
}

// ---------------------------------------------------------------------------
// Kernel 1: h = x @ W^T  (f32 in, f32 accum, bf16 h out to ws) + fused
// attention logits a_src[n,h] = <h[n,h,:], att_src[h,:]>, a_dst likewise.
// Block: 256 threads, row-tile = 32 rows, thread tile = 2 rows x 8 cols.
// W is converted to bf16 in LDS (32 KB); x staged f32 (16 KB).
// ---------------------------------------------------------------------------
__global__ __launch_bounds__(256) void k_linear(
    const float* __restrict__ x, const float* __restrict__ W,
    const float* __restrict__ att_src, const float* __restrict__ att_dst,
    bf16* __restrict__ h, float* __restrict__ a_src, float* __restrict__ a_dst) {
  __shared__ unsigned short Wt[128 * 128];  // Wt[k*128+c] = bf16(W[c][k])
  __shared__ float xs[32 * 128];
  __shared__ float ats[128], atd[128];
  const int tid = threadIdx.x;

  for (int i = tid; i < 128 * 128; i += 256) {
    int k = i >> 7, c = i & 127;
    Wt[i] = f2bu(W[c * 128 + k]);
  }
  if (tid < 128) { ats[tid] = att_src[tid]; atd[tid] = att_dst[tid]; }

  const int ct = tid & 15;   // col group: cols [ct*8, ct*8+8)
  const int rt = tid >> 4;   // row pair within tile
  const int c0 = ct * 8;
  const int head = ct >> 2;

  const int ntiles = N_ / 32;  // 3125, exact
  for (int rb = blockIdx.x; rb < ntiles; rb += gridDim.x) {
    const int row0 = rb * 32;
    __syncthreads();  // protect xs (and cover initial Wt load)
    for (int i = tid; i < 32 * 128; i += 256) {
      xs[i] = x[(row0 + (i >> 7)) * 128 + (i & 127)];
    }
    __syncthreads();

    float acc0[8], acc1[8];
#pragma unroll
    for (int j = 0; j < 8; j++) { acc0[j] = 0.f; acc1[j] = 0.f; }
    const float* x0 = &xs[(rt * 2) * 128];
    const float* x1 = x0 + 128;
#pragma unroll 8
    for (int k = 0; k < 128; k++) {
      const uint4 wv = *(const uint4*)&Wt[k * 128 + c0];
      float wc[8];
      wc[0] = u2f(wv.x << 16); wc[1] = u2f(wv.x & 0xffff0000u);
      wc[2] = u2f(wv.y << 16); wc[3] = u2f(wv.y & 0xffff0000u);
      wc[4] = u2f(wv.z << 16); wc[5] = u2f(wv.z & 0xffff0000u);
      wc[6] = u2f(wv.w << 16); wc[7] = u2f(wv.w & 0xffff0000u);
      const float xv0 = x0[k], xv1 = x1[k];
#pragma unroll
      for (int j = 0; j < 8; j++) {
        acc0[j] = fmaf(xv0, wc[j], acc0[j]);
        acc1[j] = fmaf(xv1, wc[j], acc1[j]);
      }
    }

    const int r0 = row0 + rt * 2;
#pragma unroll
    for (int j = 0; j < 8; j++) {
      h[r0 * 128 + c0 + j]       = __float2bfloat16(acc0[j]);
      h[(r0 + 1) * 128 + c0 + j] = __float2bfloat16(acc1[j]);
    }
    float ps0 = 0.f, ps1 = 0.f, pd0 = 0.f, pd1 = 0.f;
#pragma unroll
    for (int j = 0; j < 8; j++) {
      const float as_ = ats[c0 + j], ad_ = atd[c0 + j];
      ps0 += acc0[j] * as_; ps1 += acc1[j] * as_;
      pd0 += acc0[j] * ad_; pd1 += acc1[j] * ad_;
    }
    ps0 += __shfl_down(ps0, 2, 4); ps0 += __shfl_down(ps0, 1, 4);
    ps1 += __shfl_down(ps1, 2, 4); ps1 += __shfl_down(ps1, 1, 4);
    pd0 += __shfl_down(pd0, 2, 4); pd0 += __shfl_down(pd0, 1, 4);
    pd1 += __shfl_down(pd1, 2, 4); pd1 += __shfl_down(pd1, 1, 4);
    if ((ct & 3) == 0) {
      a_src[r0 * 4 + head]       = ps0;
      a_src[(r0 + 1) * 4 + head] = ps1;
      a_dst[r0 * 4 + head]       = pd0;
      a_dst[(r0 + 1) * 4 + head] = pd1;
    }
  }
}

// ---------------------------------------------------------------------------
// Kernel 2: softmax denominators. s_sum[d,h] += exp(leakyrelu(a_src[s]+a_dst[d]))
// (no max-subtraction: alpha is shift-invariant; |e| <~ 7 so exp is safe)
// ---------------------------------------------------------------------------
__global__ __launch_bounds__(256) void k_edge_sum(
    const int* __restrict__ ei, const float* __restrict__ a_src,
    const float* __restrict__ a_dst, float* __restrict__ s_sum) {
  const int e = blockIdx.x * 256 + threadIdx.x;
  if (e >= E_) return;
  const int s = ei[e], d = ei[E_ + e];
  const float4 as = *(const float4*)&a_src[s * 4];
  const float4 ad = *(const float4*)&a_dst[d * 4];
  float v0 = as.x + ad.x; v0 = (v0 > 0.f) ? v0 : 0.2f * v0;
  float v1 = as.y + ad.y; v1 = (v1 > 0.f) ? v1 : 0.2f * v1;
  float v2 = as.z + ad.z; v2 = (v2 > 0.f) ? v2 : 0.2f * v2;
  float v3 = as.w + ad.w; v3 = (v3 > 0.f) ? v3 : 0.2f * v3;
  atomicAdd(&s_sum[d * 4 + 0], __expf(v0));
  atomicAdd(&s_sum[d * 4 + 1], __expf(v1));
  atomicAdd(&s_sum[d * 4 + 2], __expf(v2));
  atomicAdd(&s_sum[d * 4 + 3], __expf(v3));
}

// ---------------------------------------------------------------------------
// Kernel 3: message scatter. One wave per edge; each lane handles 2 channels.
// accum[d,:] += h[s,:] * alpha  via f32 global atomics. accum lives in d_out.
// ---------------------------------------------------------------------------
__global__ __launch_bounds__(256) void k_scatter(
    const int* __restrict__ ei, const bf16* __restrict__ h,
    const float* __restrict__ a_src, const float* __restrict__ a_dst,
    const float* __restrict__ s_sum, float* __restrict__ accum) {
  const int lane = threadIdx.x & 63;
  const int slot = threadIdx.x >> 6;
  const int e = blockIdx.x * 4 + slot;
  if (e >= E_) return;
  const int s = ei[e], d = ei[E_ + e];
  const int head = lane >> 4;  // channels 2*lane, 2*lane+1 -> head = lane/16
  float ev = a_src[s * 4 + head] + a_dst[d * 4 + head];
  ev = (ev > 0.f) ? ev : 0.2f * ev;
  const float alpha = __expf(ev) / (s_sum[d * 4 + head] + 1e-16f);
  const __hip_bfloat162 hv = *(const __hip_bfloat162*)&h[s * 128 + lane * 2];
  const int o = d * 128 + lane * 2;
  atomicAdd(&accum[o],     __low2float(hv) * alpha);
  atomicAdd(&accum[o + 1], __high2float(hv) * alpha);
}

// ---------------------------------------------------------------------------
// Kernel 4: finalize, in place on d_out. Each thread reads only its own
// accum element before overwriting it (no cross-thread global reads).
// ---------------------------------------------------------------------------
__global__ __launch_bounds__(128) void k_final(
    const float* __restrict__ bias, const float* __restrict__ phase,
    const float* __restrict__ gamma, const float* __restrict__ beta,
    float* __restrict__ out) {
  const int n = blockIdx.x, t = threadIdx.x;
  const float v = out[n * 128 + t] + bias[t];
  float sp, cp;
  sincosf(phase[t], &sp, &cp);
  const float mag = sqrtf(v * v * (cp * cp + sp * sp) + 1e-12f);

  __shared__ float sh[2], sh2[2];
  float s = mag;
#pragma unroll
  for (int off = 32; off > 0; off >>= 1) s += __shfl_down(s, off);
  if ((t & 63) == 0) sh[t >> 6] = s;
  __syncthreads();
  const float mu = (sh[0] + sh[1]) * (1.0f / 128.0f);
  const float dv = mag - mu;
  float q = dv * dv;
#pragma unroll
  for (int off = 32; off > 0; off >>= 1) q += __shfl_down(q, off);
  if ((t & 63) == 0) sh2[t >> 6] = q;
  __syncthreads();
  const float var = (sh2[0] + sh2[1]) * (1.0f / 128.0f);
  const float hn = dv * rsqrtf(var + 1e-5f) * gamma[t] + beta[t];
  const float g = 0.5f * hn * (1.0f + erff(hn * 0.70710678118654752f));
  out[n * 128 + t] = g;
}

// ---------------------------------------------------------------------------
extern "C" void kernel_launch(void* const* d_in, const int* in_sizes, int n_in,
                              void* d_out, int out_size, void* d_ws, size_t ws_size,
                              hipStream_t stream) {
  const float* x       = (const float*)d_in[0];
  const int*   ei      = (const int*)d_in[1];
  const float* W       = (const float*)d_in[2];
  const float* att_src = (const float*)d_in[3];
  const float* att_dst = (const float*)d_in[4];
  const float* bias    = (const float*)d_in[5];
  const float* phase   = (const float*)d_in[6];
  const float* gamma   = (const float*)d_in[7];
  const float* beta    = (const float*)d_in[8];
  float* out = (float*)d_out;

  // accum (f32 N*128) lives in d_out; workspace = 30.4 MB:
  bf16*  h     = (bf16*)d_ws;                        // N*128 bf16 (25.6 MB)
  float* s_sum = (float*)(h + (size_t)N_ * D_);      // N*4 f32
  float* a_src = s_sum + (size_t)N_ * H_;            // N*4 f32
  float* a_dst = a_src + (size_t)N_ * H_;            // N*4 f32

  hipMemsetAsync(out, 0, (size_t)N_ * D_ * sizeof(float), stream);
  hipMemsetAsync(s_sum, 0, (size_t)N_ * H_ * sizeof(float), stream);

  k_linear<<<768, 256, 0, stream>>>(x, W, att_src, att_dst, h, a_src, a_dst);
  k_edge_sum<<<(E_ + 255) / 256, 256, 0, stream>>>(ei, a_src, a_dst, s_sum);
  k_scatter<<<E_ / 4, 256, 0, stream>>>(ei, h, a_src, a_dst, s_sum, out);
  k_final<<<N_, 128, 0, stream>>>(bias, phase, gamma, beta, out);
}

// Round 4
// 517.699 us; speedup vs baseline: 3.6255x; 3.6255x over previous
//
#include <hip/hip_runtime.h>
#include <hip/hip_bf16.h>

#define N_ 100000
#define E_ 1600000
#define D_ 128
#define H_ 4
#define C_ 32
#define NBLK 98  // ceil(N_/1024)

using bf16 = __hip_bfloat16;

__device__ __forceinline__ float u2f(unsigned u) { return __uint_as_float(u); }
__device__ __forceinline__ unsigned short f2bu(float v) {
  bf16 t = __float2bfloat16(v);
  return *(unsigned short*)&t;
}

// ---------------------------------------------------------------------------
// Kernel 1: h = x @ W^T  (f32 in, f32 accum, bf16 h out to ws) + fused
// attention logits a_src[n,h], a_dst[n,h]. (unchanged from round 3)
// ---------------------------------------------------------------------------
__global__ __launch_bounds__(256) void k_linear(
    const float* __restrict__ x, const float* __restrict__ W,
    const float* __restrict__ att_src, const float* __restrict__ att_dst,
    bf16* __restrict__ h, float* __restrict__ a_src, float* __restrict__ a_dst) {
  __shared__ unsigned short Wt[128 * 128];  // Wt[k*128+c] = bf16(W[c][k])
  __shared__ float xs[32 * 128];
  __shared__ float ats[128], atd[128];
  const int tid = threadIdx.x;

  for (int i = tid; i < 128 * 128; i += 256) {
    int k = i >> 7, c = i & 127;
    Wt[i] = f2bu(W[c * 128 + k]);
  }
  if (tid < 128) { ats[tid] = att_src[tid]; atd[tid] = att_dst[tid]; }

  const int ct = tid & 15;
  const int rt = tid >> 4;
  const int c0 = ct * 8;
  const int head = ct >> 2;

  const int ntiles = N_ / 32;  // 3125, exact
  for (int rb = blockIdx.x; rb < ntiles; rb += gridDim.x) {
    const int row0 = rb * 32;
    __syncthreads();
    for (int i = tid; i < 32 * 128; i += 256) {
      xs[i] = x[(row0 + (i >> 7)) * 128 + (i & 127)];
    }
    __syncthreads();

    float acc0[8], acc1[8];
#pragma unroll
    for (int j = 0; j < 8; j++) { acc0[j] = 0.f; acc1[j] = 0.f; }
    const float* x0 = &xs[(rt * 2) * 128];
    const float* x1 = x0 + 128;
#pragma unroll 8
    for (int k = 0; k < 128; k++) {
      const uint4 wv = *(const uint4*)&Wt[k * 128 + c0];
      float wc[8];
      wc[0] = u2f(wv.x << 16); wc[1] = u2f(wv.x & 0xffff0000u);
      wc[2] = u2f(wv.y << 16); wc[3] = u2f(wv.y & 0xffff0000u);
      wc[4] = u2f(wv.z << 16); wc[5] = u2f(wv.z & 0xffff0000u);
      wc[6] = u2f(wv.w << 16); wc[7] = u2f(wv.w & 0xffff0000u);
      const float xv0 = x0[k], xv1 = x1[k];
#pragma unroll
      for (int j = 0; j < 8; j++) {
        acc0[j] = fmaf(xv0, wc[j], acc0[j]);
        acc1[j] = fmaf(xv1, wc[j], acc1[j]);
      }
    }

    const int r0 = row0 + rt * 2;
#pragma unroll
    for (int j = 0; j < 8; j++) {
      h[r0 * 128 + c0 + j]       = __float2bfloat16(acc0[j]);
      h[(r0 + 1) * 128 + c0 + j] = __float2bfloat16(acc1[j]);
    }
    float ps0 = 0.f, ps1 = 0.f, pd0 = 0.f, pd1 = 0.f;
#pragma unroll
    for (int j = 0; j < 8; j++) {
      const float as_ = ats[c0 + j], ad_ = atd[c0 + j];
      ps0 += acc0[j] * as_; ps1 += acc1[j] * as_;
      pd0 += acc0[j] * ad_; pd1 += acc1[j] * ad_;
    }
    ps0 += __shfl_down(ps0, 2, 4); ps0 += __shfl_down(ps0, 1, 4);
    ps1 += __shfl_down(ps1, 2, 4); ps1 += __shfl_down(ps1, 1, 4);
    pd0 += __shfl_down(pd0, 2, 4); pd0 += __shfl_down(pd0, 1, 4);
    pd1 += __shfl_down(pd1, 2, 4); pd1 += __shfl_down(pd1, 1, 4);
    if ((ct & 3) == 0) {
      a_src[r0 * 4 + head]       = ps0;
      a_src[(r0 + 1) * 4 + head] = ps1;
      a_dst[r0 * 4 + head]       = pd0;
      a_dst[(r0 + 1) * 4 + head] = pd1;
    }
  }
}

// --------------------------- CSR construction ------------------------------
__global__ __launch_bounds__(256) void k_deg(const int* __restrict__ ei,
                                             int* __restrict__ deg) {
  const int e = blockIdx.x * 256 + threadIdx.x;
  if (e < E_) atomicAdd(&deg[ei[E_ + e]], 1);
}

// per-block inclusive scan (1024 elems/block) -> exclusive excl[], bsum[b]
__global__ __launch_bounds__(1024) void k_scan1(const int* __restrict__ deg,
                                                int* __restrict__ excl,
                                                int* __restrict__ bsum) {
  __shared__ int sh[1024];
  const int t = threadIdx.x;
  const int gid = blockIdx.x * 1024 + t;
  const int v = (gid < N_) ? deg[gid] : 0;
  sh[t] = v;
  __syncthreads();
  for (int off = 1; off < 1024; off <<= 1) {
    int add = (t >= off) ? sh[t - off] : 0;
    __syncthreads();
    sh[t] += add;
    __syncthreads();
  }
  if (gid < N_) excl[gid] = sh[t] - v;
  if (t == 1023) bsum[blockIdx.x] = sh[1023];
}

// scan the 98 block sums (single block of 128)
__global__ __launch_bounds__(128) void k_scan2(const int* __restrict__ bsum,
                                               int* __restrict__ boff) {
  __shared__ int sh[128];
  const int t = threadIdx.x;
  const int v = (t < NBLK) ? bsum[t] : 0;
  sh[t] = v;
  __syncthreads();
  for (int off = 1; off < 128; off <<= 1) {
    int add = (t >= off) ? sh[t - off] : 0;
    __syncthreads();
    sh[t] += add;
    __syncthreads();
  }
  if (t < NBLK) boff[t] = sh[t] - v;
}

// row_start = excl + boff[block]; cursor starts at row_start
__global__ __launch_bounds__(1024) void k_scan3(const int* __restrict__ excl,
                                                const int* __restrict__ boff,
                                                int* __restrict__ row_start,
                                                int* __restrict__ cursor) {
  const int gid = blockIdx.x * 1024 + threadIdx.x;
  if (gid < N_) {
    const int r = excl[gid] + boff[blockIdx.x];
    row_start[gid] = r;
    cursor[gid] = r;
  }
}

// fill: csr_src[pos] = src, pos via atomic cursor (after: cursor[d] == row end)
__global__ __launch_bounds__(256) void k_fill(const int* __restrict__ ei,
                                              int* __restrict__ cursor,
                                              int* __restrict__ csr_src) {
  const int e = blockIdx.x * 256 + threadIdx.x;
  if (e >= E_) return;
  const int s = ei[e], d = ei[E_ + e];
  const int pos = atomicAdd(&cursor[d], 1);
  csr_src[pos] = s;
}

// ---------------------------------------------------------------------------
// Gather + softmax + bias + magnitude + LayerNorm + GELU, fused.
// One wave per destination node; lane owns channels 2*lane, 2*lane+1.
// out = gelu(LN(sqrt((v cos p)^2+(v sin p)^2+eps))), v = (Σ w·h_s)/(Σ w)+bias
// ---------------------------------------------------------------------------
__global__ __launch_bounds__(256) void k_gather(
    const int* __restrict__ row_start, const int* __restrict__ row_end,
    const int* __restrict__ csr_src, const float* __restrict__ a_src,
    const float* __restrict__ a_dst, const bf16* __restrict__ h,
    const float* __restrict__ bias, const float* __restrict__ phase,
    const float* __restrict__ gamma, const float* __restrict__ beta,
    float* __restrict__ out) {
  const int lane = threadIdx.x & 63;
  const int d = blockIdx.x * 4 + (threadIdx.x >> 6);
  if (d >= N_) return;
  const int head = lane >> 4;  // channels 2*lane, 2*lane+1
  const int start = row_start[d];
  const int end = row_end[d];  // cursor after fill == end of row
  const float ad = a_dst[d * 4 + head];

  float acc0 = 0.f, acc1 = 0.f, sumw = 0.f;
  for (int base = start; base < end; base += 64) {
    const int cnt = min(64, end - base);
    const int myid = (lane < cnt) ? csr_src[base + lane] : 0;
    for (int j = 0; j < cnt; j++) {
      const int s = __shfl(myid, j);
      float ev = a_src[s * 4 + head] + ad;
      ev = (ev > 0.f) ? ev : 0.2f * ev;
      const float w = __expf(ev);
      const __hip_bfloat162 hv = *(const __hip_bfloat162*)&h[s * 128 + lane * 2];
      acc0 = fmaf(w, __low2float(hv), acc0);
      acc1 = fmaf(w, __high2float(hv), acc1);
      sumw += w;
    }
  }
  const float inv = 1.0f / (sumw + 1e-16f);
  const float2 bi = *(const float2*)&bias[lane * 2];
  const float2 ph = *(const float2*)&phase[lane * 2];
  const float v0 = acc0 * inv + bi.x;
  const float v1 = acc1 * inv + bi.y;
  float sp, cp;
  sincosf(ph.x, &sp, &cp);
  const float m0 = sqrtf(v0 * v0 * (cp * cp + sp * sp) + 1e-12f);
  sincosf(ph.y, &sp, &cp);
  const float m1 = sqrtf(v1 * v1 * (cp * cp + sp * sp) + 1e-12f);

  float s1 = m0 + m1;
#pragma unroll
  for (int off = 32; off > 0; off >>= 1) s1 += __shfl_xor(s1, off);
  const float mu = s1 * (1.0f / 128.0f);
  const float d0 = m0 - mu, d1 = m1 - mu;
  float q = d0 * d0 + d1 * d1;
#pragma unroll
  for (int off = 32; off > 0; off >>= 1) q += __shfl_xor(q, off);
  const float rstd = rsqrtf(q * (1.0f / 128.0f) + 1e-5f);
  const float2 ga = *(const float2*)&gamma[lane * 2];
  const float2 be = *(const float2*)&beta[lane * 2];
  const float hn0 = d0 * rstd * ga.x + be.x;
  const float hn1 = d1 * rstd * ga.y + be.y;
  const float g0 = 0.5f * hn0 * (1.0f + erff(hn0 * 0.70710678118654752f));
  const float g1 = 0.5f * hn1 * (1.0f + erff(hn1 * 0.70710678118654752f));
  *(float2*)&out[d * 128 + lane * 2] = make_float2(g0, g1);
}

// ---------------------------------------------------------------------------
extern "C" void kernel_launch(void* const* d_in, const int* in_sizes, int n_in,
                              void* d_out, int out_size, void* d_ws, size_t ws_size,
                              hipStream_t stream) {
  const float* x       = (const float*)d_in[0];
  const int*   ei      = (const int*)d_in[1];
  const float* W       = (const float*)d_in[2];
  const float* att_src = (const float*)d_in[3];
  const float* att_dst = (const float*)d_in[4];
  const float* bias    = (const float*)d_in[5];
  const float* phase   = (const float*)d_in[6];
  const float* gamma   = (const float*)d_in[7];
  const float* beta    = (const float*)d_in[8];
  float* out = (float*)d_out;

  // workspace (~36.8 MB)
  bf16*  h        = (bf16*)d_ws;                      // N*128 bf16 (25.6 MB)
  float* a_src    = (float*)(h + (size_t)N_ * D_);    // N*4 f32
  float* a_dst    = a_src + (size_t)N_ * H_;          // N*4 f32
  int*   deg      = (int*)(a_dst + (size_t)N_ * H_);  // N int
  int*   excl     = deg + N_;                         // N int
  int*   row_strt = excl + N_;                        // N int
  int*   cursor   = row_strt + N_;                    // N int
  int*   bsum     = cursor + N_;                      // 128 int
  int*   boff     = bsum + 128;                       // 128 int
  int*   csr_src  = boff + 128;                       // E int (6.4 MB)

  hipMemsetAsync(deg, 0, (size_t)N_ * sizeof(int), stream);

  k_linear<<<768, 256, 0, stream>>>(x, W, att_src, att_dst, h, a_src, a_dst);
  k_deg<<<(E_ + 255) / 256, 256, 0, stream>>>(ei, deg);
  k_scan1<<<NBLK, 1024, 0, stream>>>(deg, excl, bsum);
  k_scan2<<<1, 128, 0, stream>>>(bsum, boff);
  k_scan3<<<NBLK, 1024, 0, stream>>>(excl, boff, row_strt, cursor);
  k_fill<<<(E_ + 255) / 256, 256, 0, stream>>>(ei, cursor, csr_src);
  k_gather<<<(N_ + 3) / 4, 256, 0, stream>>>(row_strt, cursor, csr_src, a_src,
                                             a_dst, h, bias, phase, gamma, beta,
                                             out);
}

// Round 5
// 477.171 us; speedup vs baseline: 3.9334x; 1.0849x over previous
//
#include <hip/hip_runtime.h>
#include <hip/hip_bf16.h>

#define N_ 100000
#define E_ 1600000
#define D_ 128
#define H_ 4
#define C_ 32
#define NBLK 98  // ceil(N_/1024)

using bf16 = __hip_bfloat16;
typedef __attribute__((ext_vector_type(8))) short short8;
typedef __attribute__((ext_vector_type(4))) float f32x4;

__device__ __forceinline__ float u2f(unsigned u) { return __uint_as_float(u); }
__device__ __forceinline__ unsigned short f2bu(float v) {
  bf16 t = __float2bfloat16(v);
  return *(unsigned short*)&t;
}

// ---------------------------------------------------------------------------
// Kernel 1: h = x @ W^T via MFMA 16x16x32 bf16.
// Block = 256 thr (4 waves). Per row-block: 64 rows x 128 cols.
// WB: B fragments pre-swizzled so each lane's 8 B-elems are contiguous
//     (frag*512 + lane*8). XS: 64x128 bf16 A-tile, plain row-major.
// A-frag: m=lane&15, k=(lane>>4)*8+j.  B-frag: n=lane&15, k=(lane>>4)*8+j.
// C/D:    n=lane&15, m=(lane>>4)*4+reg.
// ---------------------------------------------------------------------------
__global__ __launch_bounds__(256) void k_linear_mfma(
    const float* __restrict__ x, const float* __restrict__ W,
    bf16* __restrict__ h) {
  __shared__ unsigned short WB[16384];    // 32 KB
  __shared__ unsigned short XS[64 * 128]; // 16 KB
  const int tid = threadIdx.x;
  const int lane = tid & 63, w = tid >> 6;
  const int n15 = lane & 15, quad = lane >> 4;

  for (int i = tid; i < 16384; i += 256) {
    const int n = i >> 7, k = i & 127;
    const int kk = k >> 5, q = (k >> 3) & 3, j = k & 7;
    const int frag = kk * 8 + (n >> 4);
    WB[frag * 512 + q * 128 + (n & 15) * 8 + j] = f2bu(W[n * 128 + k]);
  }

  const int nrb = (N_ + 63) / 64;  // 1563
  for (int rb = blockIdx.x; rb < nrb; rb += gridDim.x) {
    const int row0 = rb * 64;
    __syncthreads();  // protect XS reuse (also covers initial WB fill)
    for (int idx = tid; idx < 2048; idx += 256) {
      const int r = idx >> 5;        // 0..63
      const int c = (idx & 31) * 4;  // 0..124
      float4 xv = make_float4(0.f, 0.f, 0.f, 0.f);
      if (row0 + r < N_) xv = *(const float4*)&x[(size_t)(row0 + r) * 128 + c];
      ushort4 o;
      o.x = f2bu(xv.x); o.y = f2bu(xv.y); o.z = f2bu(xv.z); o.w = f2bu(xv.w);
      *(ushort4*)&XS[r * 128 + c] = o;
    }
    __syncthreads();

    f32x4 acc[8] = {};
    const int arow = w * 16 + n15;
#pragma unroll
    for (int kk = 0; kk < 4; kk++) {
      const short8 a = *(const short8*)&XS[arow * 128 + kk * 32 + quad * 8];
#pragma unroll
      for (int t = 0; t < 8; t++) {
        const short8 b = *(const short8*)&WB[(kk * 8 + t) * 512 + lane * 8];
        acc[t] = __builtin_amdgcn_mfma_f32_16x16x32_bf16(a, b, acc[t], 0, 0, 0);
      }
    }
#pragma unroll
    for (int t = 0; t < 8; t++) {
#pragma unroll
      for (int reg = 0; reg < 4; reg++) {
        const int grow = row0 + w * 16 + quad * 4 + reg;
        if (grow < N_)
          h[(size_t)grow * 128 + t * 16 + n15] = __float2bfloat16(acc[t][reg]);
      }
    }
  }
}

// ---------------------------------------------------------------------------
// Kernel 1b: attention logits from h. One wave per node; lane owns 2 channels.
// ---------------------------------------------------------------------------
__global__ __launch_bounds__(256) void k_logits(
    const bf16* __restrict__ h, const float* __restrict__ att_src,
    const float* __restrict__ att_dst, float* __restrict__ a_src,
    float* __restrict__ a_dst) {
  const int lane = threadIdx.x & 63;
  const int n = blockIdx.x * 4 + (threadIdx.x >> 6);
  if (n >= N_) return;
  const __hip_bfloat162 hv = *(const __hip_bfloat162*)&h[(size_t)n * 128 + lane * 2];
  const float2 as = *(const float2*)&att_src[lane * 2];
  const float2 ad = *(const float2*)&att_dst[lane * 2];
  const float h0 = __low2float(hv), h1 = __high2float(hv);
  float ps = h0 * as.x + h1 * as.y;
  float pd = h0 * ad.x + h1 * ad.y;
#pragma unroll
  for (int off = 8; off; off >>= 1) {
    ps += __shfl_xor(ps, off);
    pd += __shfl_xor(pd, off);
  }
  if ((lane & 15) == 0) {
    a_src[n * 4 + (lane >> 4)] = ps;
    a_dst[n * 4 + (lane >> 4)] = pd;
  }
}

// --------------------------- CSR construction ------------------------------
__global__ __launch_bounds__(256) void k_deg(const int* __restrict__ ei,
                                             int* __restrict__ deg) {
  const int e = blockIdx.x * 256 + threadIdx.x;
  if (e < E_) atomicAdd(&deg[ei[E_ + e]], 1);
}

__global__ __launch_bounds__(1024) void k_scan1(const int* __restrict__ deg,
                                                int* __restrict__ excl,
                                                int* __restrict__ bsum) {
  __shared__ int sh[1024];
  const int t = threadIdx.x;
  const int gid = blockIdx.x * 1024 + t;
  const int v = (gid < N_) ? deg[gid] : 0;
  sh[t] = v;
  __syncthreads();
  for (int off = 1; off < 1024; off <<= 1) {
    int add = (t >= off) ? sh[t - off] : 0;
    __syncthreads();
    sh[t] += add;
    __syncthreads();
  }
  if (gid < N_) excl[gid] = sh[t] - v;
  if (t == 1023) bsum[blockIdx.x] = sh[1023];
}

__global__ __launch_bounds__(128) void k_scan2(const int* __restrict__ bsum,
                                               int* __restrict__ boff) {
  __shared__ int sh[128];
  const int t = threadIdx.x;
  const int v = (t < NBLK) ? bsum[t] : 0;
  sh[t] = v;
  __syncthreads();
  for (int off = 1; off < 128; off <<= 1) {
    int add = (t >= off) ? sh[t - off] : 0;
    __syncthreads();
    sh[t] += add;
    __syncthreads();
  }
  if (t < NBLK) boff[t] = sh[t] - v;
}

__global__ __launch_bounds__(1024) void k_scan3(const int* __restrict__ excl,
                                                const int* __restrict__ boff,
                                                int* __restrict__ row_start,
                                                int* __restrict__ cursor) {
  const int gid = blockIdx.x * 1024 + threadIdx.x;
  if (gid < N_) {
    const int r = excl[gid] + boff[blockIdx.x];
    row_start[gid] = r;
    cursor[gid] = r;
  }
}

__global__ __launch_bounds__(256) void k_fill(const int* __restrict__ ei,
                                              int* __restrict__ cursor,
                                              int* __restrict__ csr_src) {
  const int e = blockIdx.x * 256 + threadIdx.x;
  if (e >= E_) return;
  const int s = ei[e], d = ei[E_ + e];
  const int pos = atomicAdd(&cursor[d], 1);
  csr_src[pos] = s;
}

// ---------------------------------------------------------------------------
// Gather + softmax + bias + magnitude + LayerNorm + GELU, fused.
// One wave per destination node; lane owns channels 2*lane, 2*lane+1.
// 16-edge chunks: lane (head=lane>>4, e=lane&15) computes w for its
// (edge, head) lane-parallel; accumulate loop broadcasts via shfl.
// ---------------------------------------------------------------------------
__global__ __launch_bounds__(256) void k_gather(
    const int* __restrict__ row_start, const int* __restrict__ row_end,
    const int* __restrict__ csr_src, const float* __restrict__ a_src,
    const float* __restrict__ a_dst, const bf16* __restrict__ h,
    const float* __restrict__ bias, const float* __restrict__ phase,
    const float* __restrict__ gamma, const float* __restrict__ beta,
    float* __restrict__ out) {
  const int lane = threadIdx.x & 63;
  const int d = blockIdx.x * 4 + (threadIdx.x >> 6);
  if (d >= N_) return;
  const int head = lane >> 4;
  const int e_sub = lane & 15;
  const int srcsel = lane & 48;  // head*16
  const int start = row_start[d];
  const int end = row_end[d];
  const float ad = a_dst[d * 4 + head];

  float acc0 = 0.f, acc1 = 0.f, sumw = 0.f;
  for (int base = start; base < end; base += 16) {
    const int cnt = min(16, end - base);
    const int s = (e_sub < cnt) ? csr_src[base + e_sub] : 0;
    float ev = a_src[s * 4 + head] + ad;
    ev = (ev > 0.f) ? ev : 0.2f * ev;
    const float w = __expf(ev);
    const int soff = s << 7;  // element offset of h row
    for (int j = 0; j < cnt; j++) {
      const float wj = __shfl(w, srcsel | j);
      const int oj = __shfl(soff, j);
      const __hip_bfloat162 hv = *(const __hip_bfloat162*)&h[oj + lane * 2];
      acc0 = fmaf(wj, __low2float(hv), acc0);
      acc1 = fmaf(wj, __high2float(hv), acc1);
      sumw += wj;
    }
  }
  const float inv = 1.0f / (sumw + 1e-16f);
  const float2 bi = *(const float2*)&bias[lane * 2];
  const float2 ph = *(const float2*)&phase[lane * 2];
  const float v0 = acc0 * inv + bi.x;
  const float v1 = acc1 * inv + bi.y;
  float sp, cp;
  sincosf(ph.x, &sp, &cp);
  const float m0 = sqrtf(v0 * v0 * (cp * cp + sp * sp) + 1e-12f);
  sincosf(ph.y, &sp, &cp);
  const float m1 = sqrtf(v1 * v1 * (cp * cp + sp * sp) + 1e-12f);

  float s1 = m0 + m1;
#pragma unroll
  for (int off = 32; off > 0; off >>= 1) s1 += __shfl_xor(s1, off);
  const float mu = s1 * (1.0f / 128.0f);
  const float d0 = m0 - mu, d1 = m1 - mu;
  float q = d0 * d0 + d1 * d1;
#pragma unroll
  for (int off = 32; off > 0; off >>= 1) q += __shfl_xor(q, off);
  const float rstd = rsqrtf(q * (1.0f / 128.0f) + 1e-5f);
  const float2 ga = *(const float2*)&gamma[lane * 2];
  const float2 be = *(const float2*)&beta[lane * 2];
  const float hn0 = d0 * rstd * ga.x + be.x;
  const float hn1 = d1 * rstd * ga.y + be.y;
  const float g0 = 0.5f * hn0 * (1.0f + erff(hn0 * 0.70710678118654752f));
  const float g1 = 0.5f * hn1 * (1.0f + erff(hn1 * 0.70710678118654752f));
  *(float2*)&out[d * 128 + lane * 2] = make_float2(g0, g1);
}

// ---------------------------------------------------------------------------
extern "C" void kernel_launch(void* const* d_in, const int* in_sizes, int n_in,
                              void* d_out, int out_size, void* d_ws, size_t ws_size,
                              hipStream_t stream) {
  const float* x       = (const float*)d_in[0];
  const int*   ei      = (const int*)d_in[1];
  const float* W       = (const float*)d_in[2];
  const float* att_src = (const float*)d_in[3];
  const float* att_dst = (const float*)d_in[4];
  const float* bias    = (const float*)d_in[5];
  const float* phase   = (const float*)d_in[6];
  const float* gamma   = (const float*)d_in[7];
  const float* beta    = (const float*)d_in[8];
  float* out = (float*)d_out;

  // workspace (~36.8 MB)
  bf16*  h        = (bf16*)d_ws;                      // N*128 bf16 (25.6 MB)
  float* a_src    = (float*)(h + (size_t)N_ * D_);    // N*4 f32
  float* a_dst    = a_src + (size_t)N_ * H_;          // N*4 f32
  int*   deg      = (int*)(a_dst + (size_t)N_ * H_);  // N int
  int*   excl     = deg + N_;                         // N int
  int*   row_strt = excl + N_;                        // N int
  int*   cursor   = row_strt + N_;                    // N int
  int*   bsum     = cursor + N_;                      // 128 int
  int*   boff     = bsum + 128;                       // 128 int
  int*   csr_src  = boff + 128;                       // E int (6.4 MB)

  hipMemsetAsync(deg, 0, (size_t)N_ * sizeof(int), stream);

  k_linear_mfma<<<768, 256, 0, stream>>>(x, W, h);
  k_logits<<<(N_ + 3) / 4, 256, 0, stream>>>(h, att_src, att_dst, a_src, a_dst);
  k_deg<<<(E_ + 255) / 256, 256, 0, stream>>>(ei, deg);
  k_scan1<<<NBLK, 1024, 0, stream>>>(deg, excl, bsum);
  k_scan2<<<1, 128, 0, stream>>>(bsum, boff);
  k_scan3<<<NBLK, 1024, 0, stream>>>(excl, boff, row_strt, cursor);
  k_fill<<<(E_ + 255) / 256, 256, 0, stream>>>(ei, cursor, csr_src);
  k_gather<<<(N_ + 3) / 4, 256, 0, stream>>>(row_strt, cursor, csr_src, a_src,
                                             a_dst, h, bias, phase, gamma, beta,
                                             out);
}

// Round 6
// 340.021 us; speedup vs baseline: 5.5200x; 1.4034x over previous
//
#include <hip/hip_runtime.h>
#include <hip/hip_bf16.h>

#define N_ 100000
#define E_ 1600000
#define D_ 128
#define H_ 4
#define C_ 32

using bf16 = __hip_bfloat16;
typedef __attribute__((ext_vector_type(8))) short short8;
typedef __attribute__((ext_vector_type(4))) float f32x4;

__device__ __forceinline__ float u2f(unsigned u) { return __uint_as_float(u); }
__device__ __forceinline__ unsigned short f2bu(float v) {
  bf16 t = __float2bfloat16(v);
  return *(unsigned short*)&t;
}

// ---------------------------------------------------------------------------
// Kernel 1: h = x @ W^T via MFMA 16x16x32 bf16, fused attention logits.
// Block = 256 thr (4 waves). Per row-block: 64 rows x 128 cols.
// A-frag: m=lane&15, k=(lane>>4)*8+j.  B-frag: n=lane&15, k=(lane>>4)*8+j.
// C/D:    n=lane&15, m=(lane>>4)*4+reg.
// Epilogue: LDS-transpose acc -> b128 global stores + per-head logit dots
// (head = tid&3 owns exactly channels head*32..+32, so no reduction needed).
// ---------------------------------------------------------------------------
__global__ __launch_bounds__(256) void k_linear_mfma(
    const float* __restrict__ x, const float* __restrict__ W,
    const float* __restrict__ att_src, const float* __restrict__ att_dst,
    bf16* __restrict__ h, float* __restrict__ a_src, float* __restrict__ a_dst) {
  __shared__ unsigned short WB[16384];    // 32 KB, pre-swizzled B fragments
  __shared__ unsigned short XS[64 * 128]; // 16 KB, A staging + epilogue xpose
  __shared__ float ats[128], atd[128];
  const int tid = threadIdx.x;
  const int lane = tid & 63, w = tid >> 6;
  const int n15 = lane & 15, quad = lane >> 4;

  for (int i = tid; i < 16384; i += 256) {
    const int n = i >> 7, k = i & 127;
    const int kk = k >> 5, q = (k >> 3) & 3, j = k & 7;
    const int frag = kk * 8 + (n >> 4);
    WB[frag * 512 + q * 128 + (n & 15) * 8 + j] = f2bu(W[n * 128 + k]);
  }
  if (tid < 128) { ats[tid] = att_src[tid]; atd[tid] = att_dst[tid]; }

  const int nrb = (N_ + 63) / 64;  // 1563
  for (int rb = blockIdx.x; rb < nrb; rb += gridDim.x) {
    const int row0 = rb * 64;
    __syncthreads();  // XS reuse guard (covers initial WB/ats fill too)
    for (int idx = tid; idx < 2048; idx += 256) {
      const int r = idx >> 5;
      const int c = (idx & 31) * 4;
      float4 xv = make_float4(0.f, 0.f, 0.f, 0.f);
      if (row0 + r < N_) xv = *(const float4*)&x[(size_t)(row0 + r) * 128 + c];
      ushort4 o;
      o.x = f2bu(xv.x); o.y = f2bu(xv.y); o.z = f2bu(xv.z); o.w = f2bu(xv.w);
      *(ushort4*)&XS[r * 128 + c] = o;
    }
    __syncthreads();

    f32x4 acc[8] = {};
    const int arow = w * 16 + n15;
#pragma unroll
    for (int kk = 0; kk < 4; kk++) {
      const short8 a = *(const short8*)&XS[arow * 128 + kk * 32 + quad * 8];
#pragma unroll
      for (int t = 0; t < 8; t++) {
        const short8 b = *(const short8*)&WB[(kk * 8 + t) * 512 + lane * 8];
        acc[t] = __builtin_amdgcn_mfma_f32_16x16x32_bf16(a, b, acc[t], 0, 0, 0);
      }
    }

    // transpose through XS, then vectorized stores + fused logits
    __syncthreads();
#pragma unroll
    for (int t = 0; t < 8; t++)
#pragma unroll
      for (int reg = 0; reg < 4; reg++)
        XS[(w * 16 + quad * 4 + reg) * 128 + t * 16 + n15] =
            f2bu(acc[t][reg]);
    __syncthreads();
    {
      const int row = tid >> 2;   // 0..63
      const int hd = tid & 3;     // head
      const int cb = hd * 32;
      const int grow = row0 + row;
      float ps = 0.f, pd = 0.f;
      if (grow < N_) {
#pragma unroll
        for (int g = 0; g < 4; g++) {
          const uint4 v = *(const uint4*)&XS[row * 128 + cb + g * 8];
          *(uint4*)&h[(size_t)grow * 128 + cb + g * 8] = v;
          const unsigned uu[4] = {v.x, v.y, v.z, v.w};
#pragma unroll
          for (int p = 0; p < 4; p++) {
            const float f0 = u2f(uu[p] << 16);
            const float f1 = u2f(uu[p] & 0xffff0000u);
            const int cc = cb + g * 8 + p * 2;
            ps = fmaf(f0, ats[cc], ps);     ps = fmaf(f1, ats[cc + 1], ps);
            pd = fmaf(f0, atd[cc], pd);     pd = fmaf(f1, atd[cc + 1], pd);
          }
        }
        a_src[grow * 4 + hd] = ps;
        a_dst[grow * 4 + hd] = pd;
      }
    }
  }
}

// ---------------------------------------------------------------------------
// Kernel 2: linked-list CSR build. next[e] write is COALESCED (indexed by e);
// only the atomicExch touches random memory (1.6 MB head table).
// ---------------------------------------------------------------------------
__global__ __launch_bounds__(256) void k_link(const int* __restrict__ ei,
                                              int* __restrict__ head4,
                                              int* __restrict__ nxt) {
  const int e = blockIdx.x * 256 + threadIdx.x;
  if (e >= E_) return;
  const int d = ei[E_ + e];
  const int prev = atomicExch(&head4[d * 4 + (e & 3)], e);
  nxt[e] = prev;
}

// ---------------------------------------------------------------------------
// Kernel 3: gather via 4 parallel chains per node + fused softmax, bias,
// magnitude, LayerNorm, GELU. One wave per node; lane owns 2 channels.
// Flat hop body: 4 independent next/ei/a_src/h loads issued together.
// Dead chains clamp to index 0 (L1-hot) and contribute w = 0.
// ---------------------------------------------------------------------------
__global__ __launch_bounds__(256) void k_gather_ll(
    const int* __restrict__ head4, const int* __restrict__ nxt,
    const int* __restrict__ ei, const float* __restrict__ a_src,
    const float* __restrict__ a_dst, const bf16* __restrict__ h,
    const float* __restrict__ bias, const float* __restrict__ phase,
    const float* __restrict__ gamma, const float* __restrict__ beta,
    float* __restrict__ out) {
  const int lane = threadIdx.x & 63;
  const int d = blockIdx.x * 4 + (threadIdx.x >> 6);
  if (d >= N_) return;
  const int head = lane >> 4;
  const float ad = a_dst[d * 4 + head];
  const int ch = lane * 2;

  int e0 = head4[d * 4 + 0], e1 = head4[d * 4 + 1];
  int e2 = head4[d * 4 + 2], e3 = head4[d * 4 + 3];

  float acc0 = 0.f, acc1 = 0.f, sumw = 0.f;
  while ((e0 & e1 & e2 & e3) != -1) {
    const int c0 = (e0 < 0) ? 0 : e0, c1 = (e1 < 0) ? 0 : e1;
    const int c2 = (e2 < 0) ? 0 : e2, c3 = (e3 < 0) ? 0 : e3;
    // issue all independent loads up front (4-deep memory pipeline)
    const int n0 = nxt[c0], n1 = nxt[c1], n2 = nxt[c2], n3 = nxt[c3];
    const int s0 = ei[c0], s1 = ei[c1], s2 = ei[c2], s3 = ei[c3];
    const __hip_bfloat162 h0 = *(const __hip_bfloat162*)&h[s0 * 128 + ch];
    const __hip_bfloat162 h1 = *(const __hip_bfloat162*)&h[s1 * 128 + ch];
    const __hip_bfloat162 h2 = *(const __hip_bfloat162*)&h[s2 * 128 + ch];
    const __hip_bfloat162 h3 = *(const __hip_bfloat162*)&h[s3 * 128 + ch];
    const float as0 = a_src[s0 * 4 + head], as1 = a_src[s1 * 4 + head];
    const float as2 = a_src[s2 * 4 + head], as3 = a_src[s3 * 4 + head];

    float v0 = as0 + ad; v0 = (v0 > 0.f) ? v0 : 0.2f * v0;
    float v1 = as1 + ad; v1 = (v1 > 0.f) ? v1 : 0.2f * v1;
    float v2 = as2 + ad; v2 = (v2 > 0.f) ? v2 : 0.2f * v2;
    float v3 = as3 + ad; v3 = (v3 > 0.f) ? v3 : 0.2f * v3;
    const float w0 = (e0 < 0) ? 0.f : __expf(v0);
    const float w1 = (e1 < 0) ? 0.f : __expf(v1);
    const float w2 = (e2 < 0) ? 0.f : __expf(v2);
    const float w3 = (e3 < 0) ? 0.f : __expf(v3);

    acc0 = fmaf(w0, __low2float(h0), acc0);
    acc1 = fmaf(w0, __high2float(h0), acc1);
    acc0 = fmaf(w1, __low2float(h1), acc0);
    acc1 = fmaf(w1, __high2float(h1), acc1);
    acc0 = fmaf(w2, __low2float(h2), acc0);
    acc1 = fmaf(w2, __high2float(h2), acc1);
    acc0 = fmaf(w3, __low2float(h3), acc0);
    acc1 = fmaf(w3, __high2float(h3), acc1);
    sumw += (w0 + w1) + (w2 + w3);

    e0 = (e0 < 0) ? -1 : n0;
    e1 = (e1 < 0) ? -1 : n1;
    e2 = (e2 < 0) ? -1 : n2;
    e3 = (e3 < 0) ? -1 : n3;
  }

  const float inv = 1.0f / (sumw + 1e-16f);
  const float2 bi = *(const float2*)&bias[ch];
  const float2 ph = *(const float2*)&phase[ch];
  const float v0 = acc0 * inv + bi.x;
  const float v1 = acc1 * inv + bi.y;
  float sp, cp;
  sincosf(ph.x, &sp, &cp);
  const float m0 = sqrtf(v0 * v0 * (cp * cp + sp * sp) + 1e-12f);
  sincosf(ph.y, &sp, &cp);
  const float m1 = sqrtf(v1 * v1 * (cp * cp + sp * sp) + 1e-12f);

  float s1 = m0 + m1;
#pragma unroll
  for (int off = 32; off > 0; off >>= 1) s1 += __shfl_xor(s1, off);
  const float mu = s1 * (1.0f / 128.0f);
  const float d0 = m0 - mu, d1 = m1 - mu;
  float q = d0 * d0 + d1 * d1;
#pragma unroll
  for (int off = 32; off > 0; off >>= 1) q += __shfl_xor(q, off);
  const float rstd = rsqrtf(q * (1.0f / 128.0f) + 1e-5f);
  const float2 ga = *(const float2*)&gamma[ch];
  const float2 be = *(const float2*)&beta[ch];
  const float hn0 = d0 * rstd * ga.x + be.x;
  const float hn1 = d1 * rstd * ga.y + be.y;
  const float g0 = 0.5f * hn0 * (1.0f + erff(hn0 * 0.70710678118654752f));
  const float g1 = 0.5f * hn1 * (1.0f + erff(hn1 * 0.70710678118654752f));
  *(float2*)&out[d * 128 + ch] = make_float2(g0, g1);
}

// ---------------------------------------------------------------------------
extern "C" void kernel_launch(void* const* d_in, const int* in_sizes, int n_in,
                              void* d_out, int out_size, void* d_ws, size_t ws_size,
                              hipStream_t stream) {
  const float* x       = (const float*)d_in[0];
  const int*   ei      = (const int*)d_in[1];
  const float* W       = (const float*)d_in[2];
  const float* att_src = (const float*)d_in[3];
  const float* att_dst = (const float*)d_in[4];
  const float* bias    = (const float*)d_in[5];
  const float* phase   = (const float*)d_in[6];
  const float* gamma   = (const float*)d_in[7];
  const float* beta    = (const float*)d_in[8];
  float* out = (float*)d_out;

  // workspace (36.8 MB, same footprint as rounds 3-5)
  bf16*  h     = (bf16*)d_ws;                        // N*128 bf16 (25.6 MB)
  float* a_src = (float*)(h + (size_t)N_ * D_);      // N*4 f32 (1.6 MB)
  float* a_dst = a_src + (size_t)N_ * H_;            // N*4 f32 (1.6 MB)
  int*   head4 = (int*)(a_dst + (size_t)N_ * H_);    // N*4 int (1.6 MB)
  int*   nxt   = head4 + (size_t)N_ * 4;             // E int  (6.4 MB)

  hipMemsetAsync(head4, 0xFF, (size_t)N_ * 4 * sizeof(int), stream);

  k_linear_mfma<<<768, 256, 0, stream>>>(x, W, att_src, att_dst, h, a_src,
                                         a_dst);
  k_link<<<(E_ + 255) / 256, 256, 0, stream>>>(ei, head4, nxt);
  k_gather_ll<<<(N_ + 3) / 4, 256, 0, stream>>>(head4, nxt, ei, a_src, a_dst,
                                                h, bias, phase, gamma, beta,
                                                out);
}